// Round 26
// baseline (287.778 us; speedup 1.0000x reference)
//
#include <hip/hip_runtime.h>
#include <hip/hip_bf16.h>

#define M_DIM 16384
#define K_DIM 1024
#define G_DIM 8
#define N_DIM 2048

#define BM 128
#define BN 128
#define BK 32
#define MT_PER_E 128

#define WS_NEEDED (2ull * 16777216ull * 2ull)  // two bf16 tensors, 64 MiB

typedef short bf16x8 __attribute__((ext_vector_type(8)));
typedef float f32x4 __attribute__((ext_vector_type(4)));
typedef ushort us4 __attribute__((ext_vector_type(4)));
typedef ushort us8 __attribute__((ext_vector_type(8)));
typedef uint u32x4 __attribute__((ext_vector_type(4)));

__device__ int g_bins[32];   // [0..8) counts, [8..17) offsets, [17..25) cursors
__device__ int g_perm[M_DIM];

__global__ void zero_kernel() {
    if (threadIdx.x < 32) g_bins[threadIdx.x] = 0;
}

__global__ void hist_kernel(const int* __restrict__ mi) {
    int m = blockIdx.x * blockDim.x + threadIdx.x;
    if (m < M_DIM) {
        int g = mi[m];
        if (g < 0 || g >= G_DIM) g = 0;
        atomicAdd(&g_bins[g], 1);
    }
}

__global__ void scan_kernel() {
    if (threadIdx.x == 0 && blockIdx.x == 0) {
        int off = 0; g_bins[8] = 0;
        #pragma unroll
        for (int e = 0; e < G_DIM; ++e) { off += g_bins[e]; g_bins[9 + e] = off; }
        #pragma unroll
        for (int e = 0; e < G_DIM; ++e) g_bins[17 + e] = g_bins[8 + e];
    }
}

__global__ void scatter_kernel(const int* __restrict__ mi) {
    int m = blockIdx.x * blockDim.x + threadIdx.x;
    if (m < M_DIM) {
        int g = mi[m];
        if (g < 0 || g >= G_DIM) g = 0;
        int p = atomicAdd(&g_bins[17 + g], 1);
        g_perm[p] = m;
    }
}

__device__ __forceinline__ ushort f2b(float f) {
    return (ushort)(__float_as_uint(f) >> 16);   // values bf16-exact -> exact
}

// Pure-BW pre-pack: f32 -> bf16 (grid-stride, 16B loads / 8B stores)
__global__ __launch_bounds__(256) void pack_kernel(
    const float* __restrict__ src, ushort* __restrict__ dst, int n4)
{
    int i = blockIdx.x * blockDim.x + threadIdx.x;
    for (; i < n4; i += gridDim.x * blockDim.x) {
        f32x4 v = ((const f32x4*)src)[i];
        us4 o;
        o[0] = f2b(v[0]); o[1] = f2b(v[1]); o[2] = f2b(v[2]); o[3] = f2b(v[3]);
        ((us4*)dst)[i] = o;
    }
}

__device__ __forceinline__ void gload_lds16(const ushort* g, ushort* l) {
    __builtin_amdgcn_global_load_lds(
        (const __attribute__((address_space(1))) void*)g,
        (__attribute__((address_space(3))) void*)l, 16, 0, 0);
}

// FAST PATH: bf16 inputs from ws, global_load_lds staging (address math
// proven bit-exact vs scalar reference in rounds 1-3), f32 output.
__global__ __launch_bounds__(256) void gemm_ws_kernel(
    const ushort* __restrict__ lhs,   // [M,K] bf16 (ws)
    const ushort* __restrict__ rhs,   // [G,N,K] bf16 (ws)
    float* __restrict__ out)          // [M,N] f32
{
    const int e    = blockIdx.y >> 7;
    const int tile = blockIdx.y & 127;
    const int row_start = g_bins[8 + e] + tile * BM;
    const int row_end   = g_bins[9 + e];
    if (row_start >= row_end) return;
    const int valid = min(BM, row_end - row_start);
    const int bn = blockIdx.x * BN;

    __shared__ ushort lsA[BM * BK];  // 8 KiB
    __shared__ ushort lsB[BN * BK];  // 8 KiB
    __shared__ int prow[BM];

    const int t = threadIdx.x;
    if (t < BM) prow[t] = (t < valid) ? g_perm[row_start + t] : g_perm[row_start];
    __syncthreads();

    const int srow  = t >> 2;
    const int skoff = (t & 3) * 8;
    const ushort* a0 = lhs + (size_t)prow[srow] * K_DIM + skoff;
    const ushort* a1 = lhs + (size_t)prow[64 + srow] * K_DIM + skoff;
    const ushort* rhs_e = rhs + (size_t)e * N_DIM * K_DIM;
    const ushort* b0 = rhs_e + (size_t)(bn + srow) * K_DIM + skoff;
    const ushort* b1 = rhs_e + (size_t)(bn + 64 + srow) * K_DIM + skoff;
    ushort* dA0 = lsA + t * 8;
    ushort* dA1 = lsA + 2048 + t * 8;
    ushort* dB0 = lsB + t * 8;
    ushort* dB1 = lsB + 2048 + t * 8;

    const int lane = t & 63;
    const int wave = t >> 6;
    const int wr = wave >> 1;
    const int wc = wave & 1;
    const int lr = lane & 15;
    const int ko = (lane >> 4) * 8;

    f32x4 acc[4][4] = {};

    for (int k0 = 0; k0 < K_DIM; k0 += BK) {
        gload_lds16(a0 + k0, dA0);
        gload_lds16(a1 + k0, dA1);
        gload_lds16(b0 + k0, dB0);
        gload_lds16(b1 + k0, dB1);
        __syncthreads();

        bf16x8 af[4], bfr[4];
        #pragma unroll
        for (int m = 0; m < 4; ++m)
            af[m] = *(const bf16x8*)&lsA[(wr * 64 + m * 16 + lr) * BK + ko];
        #pragma unroll
        for (int n = 0; n < 4; ++n)
            bfr[n] = *(const bf16x8*)&lsB[(wc * 64 + n * 16 + lr) * BK + ko];

        #pragma unroll
        for (int m = 0; m < 4; ++m)
            #pragma unroll
            for (int n = 0; n < 4; ++n)
                acc[m][n] = __builtin_amdgcn_mfma_f32_16x16x32_bf16(
                    af[m], bfr[n], acc[m][n], 0, 0, 0);
        __syncthreads();
    }

    #pragma unroll
    for (int m = 0; m < 4; ++m) {
        #pragma unroll
        for (int j = 0; j < 4; ++j) {
            int lrow = wr * 64 + m * 16 + (lane >> 4) * 4 + j;
            if (lrow < valid) {
                size_t grow = (size_t)prow[lrow];
                #pragma unroll
                for (int n = 0; n < 4; ++n) {
                    int gcol = bn + wc * 64 + n * 16 + (lane & 15);
                    out[grow * N_DIM + gcol] = acc[m][n][j];
                }
            }
        }
    }
}

// FALLBACK (ws too small): round-24 kernel — f32 loads, in-loop pack. 195 us.
__device__ __forceinline__ us8 pack8(const float* p) {
    f32x4 u = *(const f32x4*)p;
    f32x4 v = *(const f32x4*)(p + 4);
    us8 o;
    o[0]=f2b(u[0]); o[1]=f2b(u[1]); o[2]=f2b(u[2]); o[3]=f2b(u[3]);
    o[4]=f2b(v[0]); o[5]=f2b(v[1]); o[6]=f2b(v[2]); o[7]=f2b(v[3]);
    return o;
}

__global__ __launch_bounds__(256) void gemm_f32_kernel(
    const float* __restrict__ lhs, const float* __restrict__ rhs,
    float* __restrict__ out)
{
    const int e    = blockIdx.y >> 7;
    const int tile = blockIdx.y & 127;
    const int row_start = g_bins[8 + e] + tile * BM;
    const int row_end   = g_bins[9 + e];
    if (row_start >= row_end) return;
    const int valid = min(BM, row_end - row_start);
    const int bn = blockIdx.x * BN;

    __shared__ ushort lsA[BM * BK];
    __shared__ ushort lsB[BN * BK];
    __shared__ int prow[BM];

    const int t = threadIdx.x;
    if (t < BM) prow[t] = (t < valid) ? g_perm[row_start + t] : g_perm[row_start];
    __syncthreads();

    const int srow  = t >> 2;
    const int skoff = (t & 3) * 8;
    const float* a0 = lhs + (size_t)prow[srow] * K_DIM + skoff;
    const float* a1 = lhs + (size_t)prow[64 + srow] * K_DIM + skoff;
    const float* rhs_e = rhs + (size_t)e * N_DIM * K_DIM;
    const float* b0 = rhs_e + (size_t)(bn + srow) * K_DIM + skoff;
    const float* b1 = rhs_e + (size_t)(bn + 64 + srow) * K_DIM + skoff;

    const int lane = t & 63;
    const int wave = t >> 6;
    const int wr = wave >> 1;
    const int wc = wave & 1;
    const int lr = lane & 15;
    const int ko = (lane >> 4) * 8;

    f32x4 acc[4][4] = {};

    for (int k0 = 0; k0 < K_DIM; k0 += BK) {
        *(us8*)(lsA + t * 8)        = pack8(a0 + k0);
        *(us8*)(lsA + 2048 + t * 8) = pack8(a1 + k0);
        *(us8*)(lsB + t * 8)        = pack8(b0 + k0);
        *(us8*)(lsB + 2048 + t * 8) = pack8(b1 + k0);
        __syncthreads();

        bf16x8 af[4], bfr[4];
        #pragma unroll
        for (int m = 0; m < 4; ++m)
            af[m] = *(const bf16x8*)&lsA[(wr * 64 + m * 16 + lr) * BK + ko];
        #pragma unroll
        for (int n = 0; n < 4; ++n)
            bfr[n] = *(const bf16x8*)&lsB[(wc * 64 + n * 16 + lr) * BK + ko];

        #pragma unroll
        for (int m = 0; m < 4; ++m)
            #pragma unroll
            for (int n = 0; n < 4; ++n)
                acc[m][n] = __builtin_amdgcn_mfma_f32_16x16x32_bf16(
                    af[m], bfr[n], acc[m][n], 0, 0, 0);
        __syncthreads();
    }

    #pragma unroll
    for (int m = 0; m < 4; ++m) {
        #pragma unroll
        for (int j = 0; j < 4; ++j) {
            int lrow = wr * 64 + m * 16 + (lane >> 4) * 4 + j;
            if (lrow < valid) {
                size_t grow = (size_t)prow[lrow];
                #pragma unroll
                for (int n = 0; n < 4; ++n) {
                    int gcol = bn + wc * 64 + n * 16 + (lane & 15);
                    out[grow * N_DIM + gcol] = acc[m][n][j];
                }
            }
        }
    }
}

extern "C" void kernel_launch(void* const* d_in, const int* in_sizes, int n_in,
                              void* d_out, int out_size, void* d_ws, size_t ws_size,
                              hipStream_t stream) {
    const float* lhs = (const float*)d_in[0];
    const float* rhs = (const float*)d_in[1];
    const int* mi = (const int*)d_in[2];
    float* out = (float*)d_out;

    zero_kernel<<<1, 64, 0, stream>>>();
    hist_kernel<<<(M_DIM + 255) / 256, 256, 0, stream>>>(mi);
    scan_kernel<<<1, 64, 0, stream>>>();
    scatter_kernel<<<(M_DIM + 255) / 256, 256, 0, stream>>>(mi);

    dim3 grid(N_DIM / BN, G_DIM * MT_PER_E);

    if (ws_size >= WS_NEEDED) {
        ushort* wsA = (ushort*)d_ws;                     // [M,K] bf16
        ushort* wsB = wsA + (size_t)M_DIM * K_DIM;       // [G,N,K] bf16
        const int n4 = (M_DIM * K_DIM) / 4;              // 4,194,304
        pack_kernel<<<2048, 256, 0, stream>>>(lhs, wsA, n4);
        pack_kernel<<<2048, 256, 0, stream>>>(rhs, wsB, n4);
        gemm_ws_kernel<<<grid, 256, 0, stream>>>(wsA, wsB, out);
    } else {
        gemm_f32_kernel<<<grid, 256, 0, stream>>>(lhs, rhs, out);
    }
}